// Round 1
// baseline (162.654 us; speedup 1.0000x reference)
//
#include <hip/hip_runtime.h>
#include <float.h>
#include <stdint.h>

#define CC 256
#define HH 200
#define WW 320
#define HW (HH * WW)
#define MM 14
#define NCH 8            // channels staged per round
#define CG 4             // channel-group blocks per (roi, bin-row)
#define CPB (CC / CG)    // 64 channels per block
#define NR (CPB / NCH)   // 8 rounds
#define SP4 38           // float4 slots per (ch,row) LDS run (span4 <= 37)
#define SPF (SP4 * 4)    // 152 floats; row stride 152 % 32 = 24 -> i-pair bank split

__global__ void roi_init(float* __restrict__ binmax) {
    int t = blockIdx.x * blockDim.x + threadIdx.x;
    if (t < MM * MM) binmax[t] = -FLT_MAX;
}

__device__ inline void atomicMaxF(float* addr, float val) {
    // Ordered-int trick: valid for finite floats.
    if (val >= 0.0f) {
        atomicMax((int*)addr, __float_as_int(val));
    } else {
        atomicMin((unsigned int*)addr, __float_as_uint(val));
    }
}

__device__ __forceinline__ void gload_lds16(const float* g, float* l) {
    // 16B-per-lane DMA: LDS dest = wave-uniform base + lane*16.
    __builtin_amdgcn_global_load_lds(
        (const __attribute__((address_space(1))) unsigned int*)g,
        (__attribute__((address_space(3))) unsigned int*)l,
        16, 0, 0);
}

__global__ __launch_bounds__(256, 4) void roi_reduce(
    const float* __restrict__ feature,
    const float* __restrict__ rois,
    float* __restrict__ binmax)
{
    const int bid = blockIdx.x;
    const int cg  = bid & (CG - 1);
    const int rm  = bid >> 2;          // CG == 4
    const int m   = rm % MM;
    const int r   = rm / MM;
    const int tid = threadIdx.x;
    const int cbase = cg * CPB;

    const float ry1 = rois[r * 4 + 0];
    const float rx1 = rois[r * 4 + 1];
    const float ry2 = rois[r * 4 + 2];
    const float rx2 = rois[r * 4 + 3];
    const float sh = (ry2 - ry1) * (1.0f / 14.0f);
    const float sw = (rx2 - rx1) * (1.0f / 14.0f);
    const float f13 = 1.0f / 3.0f, f23 = 2.0f / 3.0f;

    // Two y sample coords for this bin-row m (reference clamp semantics).
    const float yA = ry1 + sh * (float)m + sh * f13;
    const float yB = ry1 + sh * (float)m + sh * f23;
    const int y1A = min(max((int)floorf(yA), 0), HH - 1);
    const int y2A = min(max((int)floorf(yA) + 1, 0), HH - 1);
    const int y1B = min(max((int)floorf(yB), 0), HH - 1);
    const int y2B = min(max((int)floorf(yB) + 1, 0), HH - 1);
    const float wyloA = yA - (float)y1A, wyhiA = (float)y2A - yA;
    const float wyloB = yB - (float)y1B, wyhiB = (float)y2B - yB;

    // Column window covering all 28 x sample points' corners, 4-aligned
    // so DMA float4 loads are 16B-aligned.
    const float xmin = rx1 + sw * f13;
    const float xmax = rx1 + sw * 13.0f + sw * f23;
    int xlo = min(max((int)floorf(xmin), 0), WW - 1);
    int xhi = min(max((int)floorf(xmax) + 1, 0), WW - 1);
    const int xlo4 = xlo & ~3;
    int span = xhi - xlo4 + 1;
    if (span > 4 * SP4 - 4) span = 4 * SP4 - 4;   // <=148; cannot trigger with given bounds
    const int span4 = (span + 3) >> 2;            // <= 37 (< SP4)

    // Compute-thread mapping: tid = s + 56*cs ; s = n*4 + j*2 + i
    const int s  = tid % 56;
    const int cs = tid / 56;        // channel sub-index 0..3 (tid>=224 -> loader-only)
    const int n  = s >> 2;
    const int j  = (s >> 1) & 1;
    const int i  = s & 1;
    const bool active = (tid < 224);

    float wxlo = 0.f, wxhi = 0.f, wylo = 0.f, wyhi = 0.f;
    int c0 = 0, c1 = 0, ra = 0, rb = 1;
    if (active) {
        float x = rx1 + sw * (float)n + sw * (j ? f23 : f13);
        int x1c = min(max((int)floorf(x), 0), WW - 1);
        int x2c = min(max((int)floorf(x) + 1, 0), WW - 1);
        wxlo = x - (float)x1c;
        wxhi = (float)x2c - x;
        c0 = min(max(x1c - xlo4, 0), span - 1);
        c1 = min(max(x2c - xlo4, 0), span - 1);
        if (i == 0) { ra = 0; rb = 1; wylo = wyloA; wyhi = wyhiA; }
        else        { ra = 2; rb = 3; wylo = wyloB; wyhi = wyhiB; }
    }

    // Double-buffered DMA tile: [buf][ch][row][SPF floats].
    // 2*8*4*152*4B = 38,912B + pmax -> 4 blocks/CU.
    __shared__ float tileF[2][NCH][4][SPF];
    __shared__ float pmax[224];

    // Loader mapping: wave rg owns one feature row; lane = float4 column.
    const int rg   = tid >> 6;
    const int lane = tid & 63;
    const int myrow = (rg == 0) ? y1A : (rg == 1) ? y2A : (rg == 2) ? y1B : y2B;
    const float* gRow = feature + cbase * HW + myrow * WW + xlo4 + (lane << 2);
    const bool ld = lane < span4;   // span4 >= 1 -> every wave issues all DMA ops

    // Prologue: stage round 0 (8 DMA ops per wave).
    if (ld) {
        const float* g = gRow;
        #pragma unroll
        for (int ch = 0; ch < NCH; ++ch) {
            gload_lds16(g, &tileF[0][ch][rg][0]);
            g += HW;
        }
    }

    float lmax = -FLT_MAX;
    for (int r8 = 0; r8 < NR; ++r8) {
        const int b = r8 & 1;
        // Issue next round's 8 DMA loads into the other buffer, then wait
        // only for the CURRENT round (counted vmcnt, never drain in-loop).
        if (r8 + 1 < NR) {
            if (ld) {
                const float* g = gRow + (r8 + 1) * NCH * HW;
                #pragma unroll
                for (int ch = 0; ch < NCH; ++ch) {
                    gload_lds16(g, &tileF[b ^ 1][ch][rg][0]);
                    g += HW;
                }
            }
            asm volatile("s_waitcnt vmcnt(8)" ::: "memory");
        } else {
            asm volatile("s_waitcnt vmcnt(0)" ::: "memory");
        }
        __builtin_amdgcn_s_barrier();          // raw barrier: no vmcnt(0) drain
        asm volatile("" ::: "memory");

        if (active) {
            #pragma unroll
            for (int q = 0; q < 2; ++q) {
                const int ch = (cs << 1) | q;
                const float* ta = &tileF[b][ch][ra][0];
                const float* tb = &tileF[b][ch][rb][0];
                float v11 = ta[c0], v12 = ta[c1];
                float v21 = tb[c0], v22 = tb[c1];
                float p  = v11 * wxhi + v12 * wxlo;
                float q2 = v21 * wxhi + v22 * wxlo;
                lmax = fmaxf(lmax, p * wyhi + q2 * wylo);
            }
        }

        asm volatile("s_waitcnt lgkmcnt(0)" ::: "memory");  // reads landed
        __builtin_amdgcn_s_barrier();          // buffer b reusable at r8+2's issue
        asm volatile("" ::: "memory");
    }

    if (active) pmax[tid] = lmax;
    __syncthreads();
    if (tid < MM) {  // one thread per bin n
        float v = -FLT_MAX;
        #pragma unroll
        for (int c4 = 0; c4 < 4; ++c4)
            #pragma unroll
            for (int q4 = 0; q4 < 4; ++q4)
                v = fmaxf(v, pmax[c4 * 56 + tid * 4 + q4]);
        atomicMaxF(&binmax[m * MM + tid], v);
    }
}

__global__ __launch_bounds__(256) void roi_bcast(
    const float* __restrict__ binmax, float4* __restrict__ out, int total4)
{
    __shared__ float4 b4[49];  // 196 floats = 49 float4, aligned with bin period
    int t = threadIdx.x;
    if (t < 49) b4[t] = ((const float4*)binmax)[t];
    __syncthreads();
    const int stride = gridDim.x * 256;
    for (int idx = blockIdx.x * 256 + t; idx < total4; idx += stride)
        out[idx] = b4[idx % 49];
}

extern "C" void kernel_launch(void* const* d_in, const int* in_sizes, int n_in,
                              void* d_out, int out_size, void* d_ws, size_t ws_size,
                              hipStream_t stream) {
    const float* feature = (const float*)d_in[0];
    const float* rois    = (const float*)d_in[1];
    float* binmax = (float*)d_ws;
    float* out    = (float*)d_out;

    const int R = in_sizes[1] / 4;

    roi_init<<<1, 256, 0, stream>>>(binmax);
    roi_reduce<<<R * MM * CG, 256, 0, stream>>>(feature, rois, binmax);

    const int total4 = out_size / 4;
    int nb = (total4 + 255) / 256;
    if (nb > 2048) nb = 2048;
    roi_bcast<<<nb, 256, 0, stream>>>(binmax, (float4*)out, total4);
}

// Round 2
// 162.433 us; speedup vs baseline: 1.0014x; 1.0014x over previous
//
#include <hip/hip_runtime.h>
#include <float.h>
#include <stdint.h>

#define CC 256
#define HH 200
#define WW 320
#define HW (HH * WW)
#define MM 14
#define NCH 4            // channels staged per round (4 -> dbuf tile fits 8 blocks/CU)
#define CG 4             // channel-group blocks per (roi, bin-row)
#define CPB (CC / CG)    // 64 channels per block
#define NR (CPB / NCH)   // 16 rounds
#define SP4 38           // float4 slots per (ch,row) LDS run (span4 <= 37)
#define SPF (SP4 * 4)    // 152 floats; row stride 152 % 32 = 24 -> i-pair bank split

__global__ void roi_init(float* __restrict__ binmax) {
    int t = blockIdx.x * blockDim.x + threadIdx.x;
    if (t < MM * MM) binmax[t] = -FLT_MAX;
}

__device__ inline void atomicMaxF(float* addr, float val) {
    // Ordered-int trick: valid for finite floats.
    if (val >= 0.0f) {
        atomicMax((int*)addr, __float_as_int(val));
    } else {
        atomicMin((unsigned int*)addr, __float_as_uint(val));
    }
}

__device__ __forceinline__ void gload_lds16(const float* g, float* l) {
    // 16B-per-lane DMA: LDS dest = wave-uniform base + lane*16.
    __builtin_amdgcn_global_load_lds(
        (const __attribute__((address_space(1))) unsigned int*)g,
        (__attribute__((address_space(3))) unsigned int*)l,
        16, 0, 0);
}

__global__ __launch_bounds__(256, 8) void roi_reduce(
    const float* __restrict__ feature,
    const float* __restrict__ rois,
    float* __restrict__ binmax)
{
    const int bid = blockIdx.x;
    const int cg  = bid & (CG - 1);
    const int rm  = bid >> 2;          // CG == 4
    const int m   = rm % MM;
    const int r   = rm / MM;
    const int tid = threadIdx.x;
    const int cbase = cg * CPB;

    const float ry1 = rois[r * 4 + 0];
    const float rx1 = rois[r * 4 + 1];
    const float ry2 = rois[r * 4 + 2];
    const float rx2 = rois[r * 4 + 3];
    const float sh = (ry2 - ry1) * (1.0f / 14.0f);
    const float sw = (rx2 - rx1) * (1.0f / 14.0f);
    const float f13 = 1.0f / 3.0f, f23 = 2.0f / 3.0f;

    // Two y sample coords for this bin-row m (reference clamp semantics).
    const float yA = ry1 + sh * (float)m + sh * f13;
    const float yB = ry1 + sh * (float)m + sh * f23;
    const int y1A = min(max((int)floorf(yA), 0), HH - 1);
    const int y2A = min(max((int)floorf(yA) + 1, 0), HH - 1);
    const int y1B = min(max((int)floorf(yB), 0), HH - 1);
    const int y2B = min(max((int)floorf(yB) + 1, 0), HH - 1);
    const float wyloA = yA - (float)y1A, wyhiA = (float)y2A - yA;
    const float wyloB = yB - (float)y1B, wyhiB = (float)y2B - yB;

    // Column window covering all 28 x sample points' corners, 4-aligned
    // so DMA float4 loads are 16B-aligned.
    const float xmin = rx1 + sw * f13;
    const float xmax = rx1 + sw * 13.0f + sw * f23;
    int xlo = min(max((int)floorf(xmin), 0), WW - 1);
    int xhi = min(max((int)floorf(xmax) + 1, 0), WW - 1);
    const int xlo4 = xlo & ~3;
    int span = xhi - xlo4 + 1;
    if (span > 4 * SP4 - 4) span = 4 * SP4 - 4;   // <=148; cannot trigger with given bounds
    const int span4 = (span + 3) >> 2;            // <= 37 (< SP4)

    // Compute-thread mapping: tid = s + 56*cs ; s = n*4 + j*2 + i
    const int s  = tid % 56;
    const int cs = tid / 56;        // channel sub-index 0..3 (tid>=224 -> loader-only)
    const int n  = s >> 2;
    const int j  = (s >> 1) & 1;
    const int i  = s & 1;
    const bool active = (tid < 224);

    float wxlo = 0.f, wxhi = 0.f, wylo = 0.f, wyhi = 0.f;
    int c0 = 0, c1 = 0, ra = 0, rb = 1;
    if (active) {
        float x = rx1 + sw * (float)n + sw * (j ? f23 : f13);
        int x1c = min(max((int)floorf(x), 0), WW - 1);
        int x2c = min(max((int)floorf(x) + 1, 0), WW - 1);
        wxlo = x - (float)x1c;
        wxhi = (float)x2c - x;
        c0 = min(max(x1c - xlo4, 0), span - 1);
        c1 = min(max(x2c - xlo4, 0), span - 1);
        if (i == 0) { ra = 0; rb = 1; wylo = wyloA; wyhi = wyhiA; }
        else        { ra = 2; rb = 3; wylo = wyloB; wyhi = wyhiB; }
    }

    // Double-buffered DMA tile: [buf][ch][row][SPF floats] = 19456 B exactly.
    // pmax is aliased into the tile after the main loop (tile dead by then),
    // keeping LDS at 19456 B -> 8 blocks/CU.
    __shared__ float tileF[2][NCH][4][SPF];
    float* pmax = &tileF[0][0][0][0];

    // Loader mapping: wave rg owns one feature row; lane = float4 column.
    const int rg   = tid >> 6;
    const int lane = tid & 63;
    const int myrow = (rg == 0) ? y1A : (rg == 1) ? y2A : (rg == 2) ? y1B : y2B;
    const float* gRow = feature + cbase * HW + myrow * WW + xlo4 + (lane << 2);
    const bool ld = lane < span4;   // span4 >= 1 -> every wave issues all DMA ops

    // Prologue: stage round 0 (NCH DMA ops per wave).
    if (ld) {
        const float* g = gRow;
        #pragma unroll
        for (int ch = 0; ch < NCH; ++ch) {
            gload_lds16(g, &tileF[0][ch][rg][0]);
            g += HW;
        }
    }

    float lmax = -FLT_MAX;
    for (int r8 = 0; r8 < NR; ++r8) {
        const int b = r8 & 1;
        // Issue next round's NCH DMA loads into the other buffer, then wait
        // only for the CURRENT round (counted vmcnt, never drain in-loop).
        if (r8 + 1 < NR) {
            if (ld) {
                const float* g = gRow + (r8 + 1) * NCH * HW;
                #pragma unroll
                for (int ch = 0; ch < NCH; ++ch) {
                    gload_lds16(g, &tileF[b ^ 1][ch][rg][0]);
                    g += HW;
                }
            }
            asm volatile("s_waitcnt vmcnt(4)" ::: "memory");
        } else {
            asm volatile("s_waitcnt vmcnt(0)" ::: "memory");
        }
        __builtin_amdgcn_s_barrier();          // raw barrier: no vmcnt(0) drain
        asm volatile("" ::: "memory");

        if (active) {
            const float* ta = &tileF[b][cs][ra][0];
            const float* tb = &tileF[b][cs][rb][0];
            float v11 = ta[c0], v12 = ta[c1];
            float v21 = tb[c0], v22 = tb[c1];
            float p  = v11 * wxhi + v12 * wxlo;
            float q2 = v21 * wxhi + v22 * wxlo;
            lmax = fmaxf(lmax, p * wyhi + q2 * wylo);
        }

        asm volatile("s_waitcnt lgkmcnt(0)" ::: "memory");  // reads landed
        __builtin_amdgcn_s_barrier();          // buffer b reusable at next issue
        asm volatile("" ::: "memory");
    }

    if (active) pmax[tid] = lmax;
    __syncthreads();
    if (tid < MM) {  // one thread per bin n
        float v = -FLT_MAX;
        #pragma unroll
        for (int c4 = 0; c4 < 4; ++c4)
            #pragma unroll
            for (int q4 = 0; q4 < 4; ++q4)
                v = fmaxf(v, pmax[c4 * 56 + tid * 4 + q4]);
        atomicMaxF(&binmax[m * MM + tid], v);
    }
}

__global__ __launch_bounds__(256) void roi_bcast(
    const float* __restrict__ binmax, float4* __restrict__ out, int total4)
{
    __shared__ float4 b4[49];  // 196 floats = 49 float4, aligned with bin period
    int t = threadIdx.x;
    if (t < 49) b4[t] = ((const float4*)binmax)[t];
    __syncthreads();
    const int stride = gridDim.x * 256;
    for (int idx = blockIdx.x * 256 + t; idx < total4; idx += stride)
        out[idx] = b4[idx % 49];
}

extern "C" void kernel_launch(void* const* d_in, const int* in_sizes, int n_in,
                              void* d_out, int out_size, void* d_ws, size_t ws_size,
                              hipStream_t stream) {
    const float* feature = (const float*)d_in[0];
    const float* rois    = (const float*)d_in[1];
    float* binmax = (float*)d_ws;
    float* out    = (float*)d_out;

    const int R = in_sizes[1] / 4;

    roi_init<<<1, 256, 0, stream>>>(binmax);
    roi_reduce<<<R * MM * CG, 256, 0, stream>>>(feature, rois, binmax);

    const int total4 = out_size / 4;
    int nb = (total4 + 255) / 256;
    if (nb > 2048) nb = 2048;
    roi_bcast<<<nb, 256, 0, stream>>>(binmax, (float4*)out, total4);
}